// Round 11
// baseline (2364.900 us; speedup 1.0000x reference)
//
#include <hip/hip_runtime.h>
#include <math.h>

#define NN 4096
#define TT 64
#define HH 128
#define NNP 4160            // hinT row stride (shorts): 8320B kills 8KB L2 set-aliasing
#define SPLITS 16
#define KPB (NN / SPLITS)   // 256 keys per phase-A block
#define KT 32
#define NTILES (KPB / KT)   // 8
#define SCALE 0.08838834764831845f   // 1/sqrt(128)
#define CSHIFT 16.0f

typedef __attribute__((ext_vector_type(8))) short short8;
typedef __attribute__((ext_vector_type(4))) float f32x4;
typedef unsigned long long u64;
#define MFMA(a, b, c) __builtin_amdgcn_mfma_f32_16x16x32_bf16((a), (b), (c), 0, 0, 0)

// ---- bf16 helpers (RNE) ----
__device__ __forceinline__ short f2b(float f) {
    union { float f; unsigned u; } v; v.f = f;
    unsigned r = v.u + 0x7fffu + ((v.u >> 16) & 1u);
    return (short)(r >> 16);
}
__device__ __forceinline__ float b2f(short s) {
    union { unsigned u; float f; } v; v.u = ((unsigned)(unsigned short)s) << 16;
    return v.f;
}
// Wave-local LDS fence (R7/R8-proven): completes ds ops + blocks compiler
// reordering of cross-lane LDS accesses without a block barrier.
__device__ __forceinline__ void lds_fence() {
    __asm__ __volatile__("s_waitcnt lgkmcnt(0)" ::: "memory");
}

// ===========================================================================
// prep: once per launch. bf16 weight transposes; hp = b_proj (h0=0);
// hinT (padded stride NNP) from x[:,0], m[:,0].
// ===========================================================================
__global__ __launch_bounds__(256) void prep_kernel(
    const float* __restrict__ x_seq, const float* __restrict__ m_seq,
    const float* __restrict__ W_in,  const float* __restrict__ b_in,
    const float* __restrict__ W_proj,const float* __restrict__ b_proj,
    const float* __restrict__ W_gcn,
    short* __restrict__ hp, short* __restrict__ hinT,
    short* __restrict__ WgT, short* __restrict__ WpT)
{
    const int b = blockIdx.x, tid = threadIdx.x;
    if (b < 256) {
        const int n0 = b * 16;
        for (int i = tid; i < 16 * HH; i += 256) {
            const int q = i >> 7, j = i & 127, n = n0 + q;
            hp[n * HH + j] = f2b(b_proj[j]);
            float hi = x_seq[n * TT] * W_in[j] + m_seq[n * TT] * W_in[HH + j] + b_in[j];
            hi = hi > 0.f ? hi : 0.f;
            hinT[(size_t)j * NNP + n] = f2b(hi);
        }
    } else {
        const int wb = b - 256;
        #pragma unroll
        for (int k = 0; k < 4; ++k) {
            const int idx = wb * 1024 + k * 256 + tid;   // = n*128 + kk
            const int n = idx >> 7, kk = idx & 127;
            WgT[idx] = f2b(W_gcn[kk * HH + n]);
            WpT[idx] = f2b(W_proj[kk * HH + n]);
        }
    }
}

// ===========================================================================
// Phase A: attention partials. 256 blocks (16 qg x 16 splits) x 512 thr
// (8 waves). Wave w owns 32 q rows (2 m-tiles); waves share the block's
// 256-key slice via LDS-staged double-buffered K/V tiles.
// R11: ONE barrier per tile (classic rotation — WAR on buf^1 is covered by
// the PREVIOUS barrier, RAW on buf by the current one); the per-wave Pt
// round-trip is ordered by wave-local lds_fence pairs instead of the old
// second barrier. Barriers/dispatch: 17 -> 9.
// Partial O -> bf16 via per-wave LDS bounce (coalesced 16B/lane stores).
// ===========================================================================
__global__ __launch_bounds__(512, 2) void attn_kernel(
    const short* __restrict__ hp, const short* __restrict__ hinT,
    short* __restrict__ OpartB, float* __restrict__ lpart)
{
    __shared__ __align__(16) char pool[58368];
    short* KtS = (short*)pool;                  // [2][32*136]  17408 B
    short* VtS = (short*)(pool + 17408);        // [2][128*40]  20480 B
    short* PtS = (short*)(pool + 37888);        // [8][32*40]   20480 B

    const int tid  = threadIdx.x;
    const int wave = tid >> 6, lane = tid & 63;
    const int ln = lane & 15, g = lane >> 4;
    const int qg = blockIdx.x >> 4, split = blockIdx.x & 15;
    const int q0 = qg * 256 + wave * 32;
    const int kbase = split * KPB;

    // staging thread maps (512 threads, 16B/lane coalesced)
    const int krow = tid >> 4, kcol = (tid & 15) * 8;   // 32 rows x 128 shorts
    const int vrow = tid >> 2, vcol = (tid & 3) * 8;    // 128 rows x 32 shorts

    // Q fragments: 2 m-tiles (A-layout: 8 contiguous bf16/lane)
    short8 qf[2][4];
    #pragma unroll
    for (int mt = 0; mt < 2; ++mt)
        #pragma unroll
        for (int kc = 0; kc < 4; ++kc)
            qf[mt][kc] = *(const short8*)&hp[(q0 + mt * 16 + ln) * HH + kc * 32 + g * 8];

    f32x4 oacc[2][8] = {};
    float lsum[2][4] = {};

    short8 ksA, vsA;
    auto load_tile = [&](int kt_) {
        const int kb = kbase + kt_ * KT;
        ksA = *(const short8*)&hp  [(kb + krow) * HH + kcol];
        vsA = *(const short8*)&hinT[(size_t)vrow * NNP + kb + vcol];
    };
    auto store_tile = [&](int b) {
        *(short8*)&KtS[b * 4352 + krow * 136 + kcol] = ksA;
        *(short8*)&VtS[b * 5120 + vrow * 40 + vcol]  = vsA;
    };

    // prologue: stage tile 0, prefetch tile 1 into regs
    load_tile(0);
    store_tile(0);
    if (NTILES > 1) load_tile(1);
    __syncthreads();   // buf0 staged

    #pragma unroll
    for (int kt = 0; kt < NTILES; ++kt) {
        const int b = kt & 1;

        // frag reads from buf b (RAW vs its staging: covered by prev barrier)
        short8 kf[2][4], vf[8];
        #pragma unroll
        for (int nt = 0; nt < 2; ++nt)
            #pragma unroll
            for (int kc = 0; kc < 4; ++kc)
                kf[nt][kc] = *(const short8*)&KtS[b * 4352 + (nt * 16 + ln) * 136 + kc * 32 + g * 8];
        #pragma unroll
        for (int dt = 0; dt < 8; ++dt)
            vf[dt] = *(const short8*)&VtS[b * 5120 + (dt * 16 + ln) * 40 + g * 8];

        // scores S[32 x 32]
        f32x4 sacc[2][2] = {};
        #pragma unroll
        for (int mt = 0; mt < 2; ++mt)
            #pragma unroll
            for (int nt = 0; nt < 2; ++nt)
                #pragma unroll
                for (int kc = 0; kc < 4; ++kc)
                    sacc[mt][nt] = MFMA(qf[mt][kc], kf[nt][kc], sacc[mt][nt]);

        lds_fence();   // WAR: prior tile's Pt A-frag reads complete (wave-local)

        // fixed-shift softmax numerators -> Pt; l sums rounded p
        #pragma unroll
        for (int mt = 0; mt < 2; ++mt)
            #pragma unroll
            for (int nt = 0; nt < 2; ++nt)
                #pragma unroll
                for (int r = 0; r < 4; ++r) {
                    const float p = __expf(sacc[mt][nt][r] * SCALE - CSHIFT);
                    const short pb = f2b(p);
                    lsum[mt][r] += b2f(pb);
                    PtS[wave * 1280 + (mt * 16 + g * 4 + r) * 40 + nt * 16 + ln] = pb;
                }

        lds_fence();   // RAW: cross-lane Pt writes before A-frag reads (R2 lesson)

        short8 pf0 = *(const short8*)&PtS[wave * 1280 + ln * 40 + g * 8];
        short8 pf1 = *(const short8*)&PtS[wave * 1280 + (16 + ln) * 40 + g * 8];

        #pragma unroll
        for (int dt = 0; dt < 8; ++dt) {
            oacc[0][dt] = MFMA(pf0, vf[dt], oacc[0][dt]);
            oacc[1][dt] = MFMA(pf1, vf[dt], oacc[1][dt]);
        }

        // stage next tile into buf b^1 (WAR: its reads preceded the PREV barrier)
        if (kt + 1 < NTILES) {
            store_tile(b ^ 1);
            if (kt + 2 < NTILES) load_tile(kt + 2);   // refill reg prefetch
        }
        __syncthreads();   // single barrier: publishes buf b^1; closes reads of buf b
    }
    // Post-loop: final barrier above guarantees ALL waves' frag reads are done
    // -> Kt/Vt reusable as per-wave bounce space without further sync.

    // l reduction over the 16-lane key dim
    #pragma unroll
    for (int mt = 0; mt < 2; ++mt)
        #pragma unroll
        for (int r = 0; r < 4; ++r) {
            float l = lsum[mt][r];
            l += __shfl_xor(l, 1); l += __shfl_xor(l, 2);
            l += __shfl_xor(l, 4); l += __shfl_xor(l, 8);
            if (ln == 0) lpart[split * NN + q0 + mt * 16 + g * 4 + r] = l;
        }

    // O partials -> bf16 via per-wave LDS bounce (coalesced 16B/lane stores)
    short* bounce = (short*)pool + wave * 2048;   // 4KB/wave in dead Kt/Vt
    #pragma unroll
    for (int mt = 0; mt < 2; ++mt) {
        #pragma unroll
        for (int dt = 0; dt < 8; ++dt)
            #pragma unroll
            for (int r = 0; r < 4; ++r)
                bounce[(g * 4 + r) * 128 + dt * 16 + ln] = f2b(oacc[mt][dt][r]);
        lds_fence();   // RAW: cross-lane bounce writes before row reads
        #pragma unroll
        for (int sub = 0; sub < 4; ++sub) {
            const int qrow = sub * 4 + (lane >> 4), chunk = lane & 15;
            const short8 rd = *(const short8*)&bounce[qrow * 128 + chunk * 8];
            *(short8*)&OpartB[((size_t)split * NN + q0 + mt * 16 + qrow) * HH + chunk * 8] = rd;
        }
        lds_fence();   // WAR before next mt overwrites the bounce
    }
}

// ===========================================================================
// Phase B: merge 16 bf16 partials -> msg; h_new = relu(msg@Wg+b_gcn+h_in(t));
// pred -> out[:,t]; h_proj(t+1) -> hp; h_in(t+1) -> hinT (recomputed, bf16-
// rounding parity). 256 blocks x 256 thr.
// ===========================================================================
__global__ __launch_bounds__(256) void fuse_kernel(
    const short* __restrict__ OpartB, const float* __restrict__ lpart,
    short* __restrict__ hp, short* __restrict__ hinT,
    const short* __restrict__ WgT, const short* __restrict__ WpT,
    const float* __restrict__ b_gcn, const float* __restrict__ b_proj,
    const float* __restrict__ W_out, const float* __restrict__ b_out,
    const float* __restrict__ x_seq, const float* __restrict__ m_seq,
    const float* __restrict__ W_in,  const float* __restrict__ b_in,
    float* __restrict__ out, int t)
{
    __shared__ __align__(16) short msgb[16 * 136];
    __shared__ __align__(16) short hnb[16 * 136];
    __shared__ __align__(16) short hintb[128 * 16];
    __shared__ float larr[16];
    __shared__ float ppd[4 * 16];

    const int tid = threadIdx.x;
    const int wave = tid >> 6, lane = tid & 63;
    const int ln = lane & 15, g = lane >> 4;
    const int qb = blockIdx.x * 16;

    if (tid < 16) {
        float l = 0.f;
        #pragma unroll
        for (int sp = 0; sp < SPLITS; ++sp) l += lpart[sp * NN + qb + tid];
        larr[tid] = 1.0f / l;
    }
    __syncthreads();

    // merge 16 bf16 partials -> msg (short8 coalesced reads, fp32 accumulate)
    {
        const int q = tid >> 4, c8 = (tid & 15) * 8;   // 256 thr = 16q x 16 chunks
        float s[8] = {0.f, 0.f, 0.f, 0.f, 0.f, 0.f, 0.f, 0.f};
        #pragma unroll
        for (int sp = 0; sp < SPLITS; ++sp) {
            const short8 v = *(const short8*)&OpartB[((size_t)sp * NN + qb + q) * HH + c8];
            #pragma unroll
            for (int k = 0; k < 8; ++k) s[k] += b2f(v[k]);
        }
        const float inv = larr[q];
        short* mp = &msgb[q * 136 + c8];
        #pragma unroll
        for (int k = 0; k < 8; ++k) mp[k] = f2b(s[k] * inv);
    }
    __syncthreads();

    // GEMM1: h_new = relu(msg @ W_gcn + b_gcn + h_in(t)); pred partials
    short8 af[4];
    #pragma unroll
    for (int kc = 0; kc < 4; ++kc)
        af[kc] = *(const short8*)&msgb[ln * 136 + kc * 32 + g * 8];
    float pr[4] = {0.f, 0.f, 0.f, 0.f};
    #pragma unroll
    for (int ni = 0; ni < 2; ++ni) {
        const int nt = wave * 2 + ni;
        f32x4 c = {};
        #pragma unroll
        for (int kc = 0; kc < 4; ++kc)
            c = MFMA(af[kc], *(const short8*)&WgT[(nt * 16 + ln) * HH + kc * 32 + g * 8], c);
        const int j = nt * 16 + ln;
        const float bg = b_gcn[j], wo = W_out[j];
        const float wj0 = W_in[j], wj1 = W_in[HH + j], bj = b_in[j];
        #pragma unroll
        for (int r = 0; r < 4; ++r) {
            const int q = g * 4 + r;
            float hi = x_seq[(qb + q) * TT + t] * wj0 + m_seq[(qb + q) * TT + t] * wj1 + bj;
            hi = hi > 0.f ? hi : 0.f;
            float v = c[r] + bg + b2f(f2b(hi));
            v = v > 0.f ? v : 0.f;
            hnb[q * 136 + j] = f2b(v);
            pr[r] += v * wo;
        }
    }
    #pragma unroll
    for (int r = 0; r < 4; ++r) {
        float p = pr[r];
        p += __shfl_xor(p, 1); p += __shfl_xor(p, 2);
        p += __shfl_xor(p, 4); p += __shfl_xor(p, 8);
        if (ln == 0) ppd[wave * 16 + g * 4 + r] = p;
    }
    __syncthreads();   // hnb + ppd complete

    if (tid < 16)
        out[(qb + tid) * TT + t] = ppd[tid] + ppd[16 + tid] + ppd[32 + tid] + ppd[48 + tid] + b_out[0];

    if (t < TT - 1) {
        // GEMM2: h_proj(t+1) = h_new @ W_proj + b_proj -> hp
        short8 hf[4];
        #pragma unroll
        for (int kc = 0; kc < 4; ++kc)
            hf[kc] = *(const short8*)&hnb[ln * 136 + kc * 32 + g * 8];
        #pragma unroll
        for (int ni = 0; ni < 2; ++ni) {
            const int nt = wave * 2 + ni;
            f32x4 c = {};
            #pragma unroll
            for (int kc = 0; kc < 4; ++kc)
                c = MFMA(hf[kc], *(const short8*)&WpT[(nt * 16 + ln) * HH + kc * 32 + g * 8], c);
            const float bp = b_proj[nt * 16 + ln];
            #pragma unroll
            for (int r = 0; r < 4; ++r)
                hp[(qb + g * 4 + r) * HH + nt * 16 + ln] = f2b(c[r] + bp);
        }

        // h_in(t+1): LDS transpose then 8B-chunk stores into padded hinT
        for (int i = tid; i < 16 * HH; i += 256) {
            const int q = i >> 7, j = i & 127;
            float hi = x_seq[(qb + q) * TT + t + 1] * W_in[j]
                     + m_seq[(qb + q) * TT + t + 1] * W_in[HH + j] + b_in[j];
            hi = hi > 0.f ? hi : 0.f;
            hintb[j * 16 + q] = f2b(hi);
        }
        __syncthreads();
        for (int c = tid; c < 512; c += 256) {
            const int j = c >> 2, off = (c & 3) * 4;
            *(u64*)&hinT[(size_t)j * NNP + qb + off] = *(const u64*)&hintb[j * 16 + off];
        }
    }
}

// ===========================================================================
extern "C" void kernel_launch(void* const* d_in, const int* in_sizes, int n_in,
                              void* d_out, int out_size, void* d_ws, size_t ws_size,
                              hipStream_t stream) {
    const float* x_seq  = (const float*)d_in[0];
    const float* m_seq  = (const float*)d_in[1];
    const float* W_in   = (const float*)d_in[2];
    const float* b_in   = (const float*)d_in[3];
    const float* W_proj = (const float*)d_in[4];
    const float* b_proj = (const float*)d_in[5];
    const float* W_gcn  = (const float*)d_in[6];
    const float* b_gcn  = (const float*)d_in[7];
    const float* W_out  = (const float*)d_in[8];
    const float* b_out  = (const float*)d_in[9];
    float* out = (float*)d_out;

    // ws carve (~20 MB): hp | hinT(padded) | WgT | WpT | lpart | OpartB
    char* base = (char*)d_ws;
    const size_t MB = 1 << 20;
    short* hp     = (short*)(base + 0 * MB);
    short* hinT   = (short*)(base + 1 * MB);           // 128*4160*2 B
    short* WgT    = (short*)(base + 3 * MB);
    short* WpT    = (short*)(base + 3 * MB + 32768);
    float* lpart  = (float*)(base + 3 * MB + 65536);   // 16*4096*4 = 256 KB
    short* OpartB = (short*)(base + 4 * MB);           // 16*4096*128*2 = 16 MB

    prep_kernel<<<272, 256, 0, stream>>>(x_seq, m_seq, W_in, b_in, W_proj, b_proj,
                                         W_gcn, hp, hinT, WgT, WpT);

    for (int t = 0; t < TT; ++t) {
        attn_kernel<<<(NN / 256) * SPLITS, 512, 0, stream>>>(hp, hinT, OpartB, lpart);
        fuse_kernel<<<NN / 16, 256, 0, stream>>>(OpartB, lpart, hp, hinT,
                                                 WgT, WpT, b_gcn, b_proj, W_out, b_out,
                                                 x_seq, m_seq, W_in, b_in, out, t);
    }
}

// Round 12
// 2186.150 us; speedup vs baseline: 1.0818x; 1.0818x over previous
//
#include <hip/hip_runtime.h>
#include <math.h>

#define NN 4096
#define TT 64
#define HH 128
#define NNP 4160            // hinT row stride (shorts): 8320B kills 8KB L2 set-aliasing
#define SPLITS 16
#define KPB (NN / SPLITS)   // 256 keys per phase-A block
#define KT 32
#define NTILES (KPB / KT)   // 8
#define SCALE 0.08838834764831845f   // 1/sqrt(128)
#define CSHIFT 16.0f

typedef __attribute__((ext_vector_type(8))) short short8;
typedef __attribute__((ext_vector_type(4))) float f32x4;
typedef unsigned long long u64;
#define MFMA(a, b, c) __builtin_amdgcn_mfma_f32_16x16x32_bf16((a), (b), (c), 0, 0, 0)

// ---- bf16 helpers (RNE) ----
__device__ __forceinline__ short f2b(float f) {
    union { float f; unsigned u; } v; v.f = f;
    unsigned r = v.u + 0x7fffu + ((v.u >> 16) & 1u);
    return (short)(r >> 16);
}
__device__ __forceinline__ float b2f(short s) {
    union { unsigned u; float f; } v; v.u = ((unsigned)(unsigned short)s) << 16;
    return v.f;
}
// Wave-local LDS fence (R7/R8-proven): completes ds ops + blocks compiler
// reordering of cross-lane LDS accesses without a block barrier.
__device__ __forceinline__ void lds_fence() {
    __asm__ __volatile__("s_waitcnt lgkmcnt(0)" ::: "memory");
}

// ===========================================================================
// prep: once per launch. bf16 weight transposes; hp = b_proj (h0=0);
// hinT (padded stride NNP) from x[:,0], m[:,0].
// ===========================================================================
__global__ __launch_bounds__(256) void prep_kernel(
    const float* __restrict__ x_seq, const float* __restrict__ m_seq,
    const float* __restrict__ W_in,  const float* __restrict__ b_in,
    const float* __restrict__ W_proj,const float* __restrict__ b_proj,
    const float* __restrict__ W_gcn,
    short* __restrict__ hp, short* __restrict__ hinT,
    short* __restrict__ WgT, short* __restrict__ WpT)
{
    const int b = blockIdx.x, tid = threadIdx.x;
    if (b < 256) {
        const int n0 = b * 16;
        for (int i = tid; i < 16 * HH; i += 256) {
            const int q = i >> 7, j = i & 127, n = n0 + q;
            hp[n * HH + j] = f2b(b_proj[j]);
            float hi = x_seq[n * TT] * W_in[j] + m_seq[n * TT] * W_in[HH + j] + b_in[j];
            hi = hi > 0.f ? hi : 0.f;
            hinT[(size_t)j * NNP + n] = f2b(hi);
        }
    } else {
        const int wb = b - 256;
        #pragma unroll
        for (int k = 0; k < 4; ++k) {
            const int idx = wb * 1024 + k * 256 + tid;   // = n*128 + kk
            const int n = idx >> 7, kk = idx & 127;
            WgT[idx] = f2b(W_gcn[kk * HH + n]);
            WpT[idx] = f2b(W_proj[kk * HH + n]);
        }
    }
}

// ===========================================================================
// Phase A: attention partials. 256 blocks (16 qg x 16 splits) x 512 thr
// (8 waves). Wave w owns 32 q rows [qg*256+32w, +32) (2 m-tiles); all waves
// share the block's 256-key slice via LDS-staged double-buffered K/V tiles
// (2 barriers/tile; they also serialize the per-wave Pt round-trip).
// R12 NOTE: this is the R10 schedule, reverted verbatim after R11's
// 1-barrier + full-unroll variant regressed 8% — the mid-body placement of
// load_tile (global loads issued a full compute phase before the barrier's
// vmcnt(0) drain) is what matters, not the barrier count.
// QB=KPB=256 is the traffic-optimal 256-block tiling: K/V 32 MB/step.
// blockIdx&15=split with 8 XCDs pins each split's 16 blocks to one XCD —
// L2-optimal K/V sharing for free.
// Partial O -> bf16 via per-wave LDS bounce (coalesced 16B/lane stores).
// ===========================================================================
__global__ __launch_bounds__(512, 2) void attn_kernel(
    const short* __restrict__ hp, const short* __restrict__ hinT,
    short* __restrict__ OpartB, float* __restrict__ lpart)
{
    __shared__ __align__(16) char pool[58368];
    short* KtS = (short*)pool;                  // [2][32*136]  17408 B
    short* VtS = (short*)(pool + 17408);        // [2][128*40]  20480 B
    short* PtS = (short*)(pool + 37888);        // [8][32*40]   20480 B

    const int tid  = threadIdx.x;
    const int wave = tid >> 6, lane = tid & 63;
    const int ln = lane & 15, g = lane >> 4;
    const int qg = blockIdx.x >> 4, split = blockIdx.x & 15;
    const int q0 = qg * 256 + wave * 32;
    const int kbase = split * KPB;

    // staging thread maps (512 threads, 16B/lane coalesced)
    const int krow = tid >> 4, kcol = (tid & 15) * 8;   // 32 rows x 128 shorts
    const int vrow = tid >> 2, vcol = (tid & 3) * 8;    // 128 rows x 32 shorts

    // Q fragments: 2 m-tiles (A-layout: 8 contiguous bf16/lane)
    short8 qf[2][4];
    #pragma unroll
    for (int mt = 0; mt < 2; ++mt)
        #pragma unroll
        for (int kc = 0; kc < 4; ++kc)
            qf[mt][kc] = *(const short8*)&hp[(q0 + mt * 16 + ln) * HH + kc * 32 + g * 8];

    f32x4 oacc[2][8] = {};
    float lsum[2][4] = {};

    short8 ksA, vsA;
    auto load_tile = [&](int kt_) {
        const int kb = kbase + kt_ * KT;
        ksA = *(const short8*)&hp  [(kb + krow) * HH + kcol];
        vsA = *(const short8*)&hinT[(size_t)vrow * NNP + kb + vcol];
    };
    auto store_tile = [&](int b) {
        *(short8*)&KtS[b * 4352 + krow * 136 + kcol] = ksA;
        *(short8*)&VtS[b * 5120 + vrow * 40 + vcol]  = vsA;
    };

    load_tile(0);
    store_tile(0);

    for (int kt = 0; kt < NTILES; ++kt) {
        const int b = kt & 1;
        __syncthreads();   // buf b staged; prev iter's Pt/frag reads done (WAR)

        short8 kf[2][4], vf[8];
        #pragma unroll
        for (int nt = 0; nt < 2; ++nt)
            #pragma unroll
            for (int kc = 0; kc < 4; ++kc)
                kf[nt][kc] = *(const short8*)&KtS[b * 4352 + (nt * 16 + ln) * 136 + kc * 32 + g * 8];
        #pragma unroll
        for (int dt = 0; dt < 8; ++dt)
            vf[dt] = *(const short8*)&VtS[b * 5120 + (dt * 16 + ln) * 40 + g * 8];

        if (kt + 1 < NTILES) load_tile(kt + 1);   // global -> regs, overlaps compute

        // scores S[32 x 32]
        f32x4 sacc[2][2] = {};
        #pragma unroll
        for (int mt = 0; mt < 2; ++mt)
            #pragma unroll
            for (int nt = 0; nt < 2; ++nt)
                #pragma unroll
                for (int kc = 0; kc < 4; ++kc)
                    sacc[mt][nt] = MFMA(qf[mt][kc], kf[nt][kc], sacc[mt][nt]);

        // fixed-shift softmax numerators -> Pt; l sums rounded p
        #pragma unroll
        for (int mt = 0; mt < 2; ++mt)
            #pragma unroll
            for (int nt = 0; nt < 2; ++nt)
                #pragma unroll
                for (int r = 0; r < 4; ++r) {
                    const float p = __expf(sacc[mt][nt][r] * SCALE - CSHIFT);
                    const short pb = f2b(p);
                    lsum[mt][r] += b2f(pb);
                    PtS[wave * 1280 + (mt * 16 + g * 4 + r) * 40 + nt * 16 + ln] = pb;
                }

        if (kt + 1 < NTILES) store_tile(b ^ 1);

        __syncthreads();   // Pt RAW fence + next buf fully staged

        short8 pf0 = *(const short8*)&PtS[wave * 1280 + ln * 40 + g * 8];
        short8 pf1 = *(const short8*)&PtS[wave * 1280 + (16 + ln) * 40 + g * 8];

        #pragma unroll
        for (int dt = 0; dt < 8; ++dt) {
            oacc[0][dt] = MFMA(pf0, vf[dt], oacc[0][dt]);
            oacc[1][dt] = MFMA(pf1, vf[dt], oacc[1][dt]);
        }
    }
    // After the loop Kt/Vt are dead for ALL waves (frag reads precede the
    // final 2nd barrier) -> safe to reuse as per-wave bounce, no extra sync.

    // l reduction over the 16-lane key dim
    #pragma unroll
    for (int mt = 0; mt < 2; ++mt)
        #pragma unroll
        for (int r = 0; r < 4; ++r) {
            float l = lsum[mt][r];
            l += __shfl_xor(l, 1); l += __shfl_xor(l, 2);
            l += __shfl_xor(l, 4); l += __shfl_xor(l, 8);
            if (ln == 0) lpart[split * NN + q0 + mt * 16 + g * 4 + r] = l;
        }

    // O partials -> bf16 via per-wave LDS bounce (coalesced 16B/lane stores)
    short* bounce = (short*)pool + wave * 2048;   // 4KB/wave in dead Kt/Vt
    #pragma unroll
    for (int mt = 0; mt < 2; ++mt) {
        #pragma unroll
        for (int dt = 0; dt < 8; ++dt)
            #pragma unroll
            for (int r = 0; r < 4; ++r)
                bounce[(g * 4 + r) * 128 + dt * 16 + ln] = f2b(oacc[mt][dt][r]);
        lds_fence();   // RAW: cross-lane bounce writes before row reads
        #pragma unroll
        for (int sub = 0; sub < 4; ++sub) {
            const int qrow = sub * 4 + (lane >> 4), chunk = lane & 15;
            const short8 rd = *(const short8*)&bounce[qrow * 128 + chunk * 8];
            *(short8*)&OpartB[((size_t)split * NN + q0 + mt * 16 + qrow) * HH + chunk * 8] = rd;
        }
        lds_fence();   // WAR before next mt overwrites the bounce
    }
}

// ===========================================================================
// Phase B: merge 16 bf16 partials -> msg; h_new = relu(msg@Wg+b_gcn+h_in(t));
// pred -> out[:,t]; h_proj(t+1) -> hp; h_in(t+1) -> hinT (recomputed, bf16-
// rounding parity). 256 blocks x 256 thr.
// ===========================================================================
__global__ __launch_bounds__(256) void fuse_kernel(
    const short* __restrict__ OpartB, const float* __restrict__ lpart,
    short* __restrict__ hp, short* __restrict__ hinT,
    const short* __restrict__ WgT, const short* __restrict__ WpT,
    const float* __restrict__ b_gcn, const float* __restrict__ b_proj,
    const float* __restrict__ W_out, const float* __restrict__ b_out,
    const float* __restrict__ x_seq, const float* __restrict__ m_seq,
    const float* __restrict__ W_in,  const float* __restrict__ b_in,
    float* __restrict__ out, int t)
{
    __shared__ __align__(16) short msgb[16 * 136];
    __shared__ __align__(16) short hnb[16 * 136];
    __shared__ __align__(16) short hintb[128 * 16];
    __shared__ float larr[16];
    __shared__ float ppd[4 * 16];

    const int tid = threadIdx.x;
    const int wave = tid >> 6, lane = tid & 63;
    const int ln = lane & 15, g = lane >> 4;
    const int qb = blockIdx.x * 16;

    if (tid < 16) {
        float l = 0.f;
        #pragma unroll
        for (int sp = 0; sp < SPLITS; ++sp) l += lpart[sp * NN + qb + tid];
        larr[tid] = 1.0f / l;
    }
    __syncthreads();

    // merge 16 bf16 partials -> msg (short8 coalesced reads, fp32 accumulate)
    {
        const int q = tid >> 4, c8 = (tid & 15) * 8;   // 256 thr = 16q x 16 chunks
        float s[8] = {0.f, 0.f, 0.f, 0.f, 0.f, 0.f, 0.f, 0.f};
        #pragma unroll
        for (int sp = 0; sp < SPLITS; ++sp) {
            const short8 v = *(const short8*)&OpartB[((size_t)sp * NN + qb + q) * HH + c8];
            #pragma unroll
            for (int k = 0; k < 8; ++k) s[k] += b2f(v[k]);
        }
        const float inv = larr[q];
        short* mp = &msgb[q * 136 + c8];
        #pragma unroll
        for (int k = 0; k < 8; ++k) mp[k] = f2b(s[k] * inv);
    }
    __syncthreads();

    // GEMM1: h_new = relu(msg @ W_gcn + b_gcn + h_in(t)); pred partials
    short8 af[4];
    #pragma unroll
    for (int kc = 0; kc < 4; ++kc)
        af[kc] = *(const short8*)&msgb[ln * 136 + kc * 32 + g * 8];
    float pr[4] = {0.f, 0.f, 0.f, 0.f};
    #pragma unroll
    for (int ni = 0; ni < 2; ++ni) {
        const int nt = wave * 2 + ni;
        f32x4 c = {};
        #pragma unroll
        for (int kc = 0; kc < 4; ++kc)
            c = MFMA(af[kc], *(const short8*)&WgT[(nt * 16 + ln) * HH + kc * 32 + g * 8], c);
        const int j = nt * 16 + ln;
        const float bg = b_gcn[j], wo = W_out[j];
        const float wj0 = W_in[j], wj1 = W_in[HH + j], bj = b_in[j];
        #pragma unroll
        for (int r = 0; r < 4; ++r) {
            const int q = g * 4 + r;
            float hi = x_seq[(qb + q) * TT + t] * wj0 + m_seq[(qb + q) * TT + t] * wj1 + bj;
            hi = hi > 0.f ? hi : 0.f;
            float v = c[r] + bg + b2f(f2b(hi));
            v = v > 0.f ? v : 0.f;
            hnb[q * 136 + j] = f2b(v);
            pr[r] += v * wo;
        }
    }
    #pragma unroll
    for (int r = 0; r < 4; ++r) {
        float p = pr[r];
        p += __shfl_xor(p, 1); p += __shfl_xor(p, 2);
        p += __shfl_xor(p, 4); p += __shfl_xor(p, 8);
        if (ln == 0) ppd[wave * 16 + g * 4 + r] = p;
    }
    __syncthreads();   // hnb + ppd complete

    if (tid < 16)
        out[(qb + tid) * TT + t] = ppd[tid] + ppd[16 + tid] + ppd[32 + tid] + ppd[48 + tid] + b_out[0];

    if (t < TT - 1) {
        // GEMM2: h_proj(t+1) = h_new @ W_proj + b_proj -> hp
        short8 hf[4];
        #pragma unroll
        for (int kc = 0; kc < 4; ++kc)
            hf[kc] = *(const short8*)&hnb[ln * 136 + kc * 32 + g * 8];
        #pragma unroll
        for (int ni = 0; ni < 2; ++ni) {
            const int nt = wave * 2 + ni;
            f32x4 c = {};
            #pragma unroll
            for (int kc = 0; kc < 4; ++kc)
                c = MFMA(hf[kc], *(const short8*)&WpT[(nt * 16 + ln) * HH + kc * 32 + g * 8], c);
            const float bp = b_proj[nt * 16 + ln];
            #pragma unroll
            for (int r = 0; r < 4; ++r)
                hp[(qb + g * 4 + r) * HH + nt * 16 + ln] = f2b(c[r] + bp);
        }

        // h_in(t+1): LDS transpose then 8B-chunk stores into padded hinT
        for (int i = tid; i < 16 * HH; i += 256) {
            const int q = i >> 7, j = i & 127;
            float hi = x_seq[(qb + q) * TT + t + 1] * W_in[j]
                     + m_seq[(qb + q) * TT + t + 1] * W_in[HH + j] + b_in[j];
            hi = hi > 0.f ? hi : 0.f;
            hintb[j * 16 + q] = f2b(hi);
        }
        __syncthreads();
        for (int c = tid; c < 512; c += 256) {
            const int j = c >> 2, off = (c & 3) * 4;
            *(u64*)&hinT[(size_t)j * NNP + qb + off] = *(const u64*)&hintb[j * 16 + off];
        }
    }
}

// ===========================================================================
extern "C" void kernel_launch(void* const* d_in, const int* in_sizes, int n_in,
                              void* d_out, int out_size, void* d_ws, size_t ws_size,
                              hipStream_t stream) {
    const float* x_seq  = (const float*)d_in[0];
    const float* m_seq  = (const float*)d_in[1];
    const float* W_in   = (const float*)d_in[2];
    const float* b_in   = (const float*)d_in[3];
    const float* W_proj = (const float*)d_in[4];
    const float* b_proj = (const float*)d_in[5];
    const float* W_gcn  = (const float*)d_in[6];
    const float* b_gcn  = (const float*)d_in[7];
    const float* W_out  = (const float*)d_in[8];
    const float* b_out  = (const float*)d_in[9];
    float* out = (float*)d_out;

    // ws carve (~20 MB): hp | hinT(padded) | WgT | WpT | lpart | OpartB
    char* base = (char*)d_ws;
    const size_t MB = 1 << 20;
    short* hp     = (short*)(base + 0 * MB);
    short* hinT   = (short*)(base + 1 * MB);           // 128*4160*2 B
    short* WgT    = (short*)(base + 3 * MB);
    short* WpT    = (short*)(base + 3 * MB + 32768);
    float* lpart  = (float*)(base + 3 * MB + 65536);   // 16*4096*4 = 256 KB
    short* OpartB = (short*)(base + 4 * MB);           // 16*4096*128*2 = 16 MB

    prep_kernel<<<272, 256, 0, stream>>>(x_seq, m_seq, W_in, b_in, W_proj, b_proj,
                                         W_gcn, hp, hinT, WgT, WpT);

    for (int t = 0; t < TT; ++t) {
        attn_kernel<<<(NN / 256) * SPLITS, 512, 0, stream>>>(hp, hinT, OpartB, lpart);
        fuse_kernel<<<NN / 16, 256, 0, stream>>>(OpartB, lpart, hp, hinT,
                                                 WgT, WpT, b_gcn, b_proj, W_out, b_out,
                                                 x_seq, m_seq, W_in, b_in, out, t);
    }
}